// Round 1
// baseline (211.253 us; speedup 1.0000x reference)
//
#include <hip/hip_runtime.h>

#define NBINS   4096
#define NSLICE  16      // B*C = 4*4
#define BPS     64      // blocks per slice
#define BLOCK   256

static constexpr float kRange = 9.2104f;   // ce < -ln(1e-4) = 9.21034

// ws layout (bytes):
//  [0)            hist_cnt : NSLICE*NBINS u32   = 262144
//  [262144)       hist_sum : NSLICE*NBINS f32   = 262144
//  [524288)       tmax     : NSLICE u32 (float bits)
//  [524352)       pmax     : NSLICE u32
//  [524416)       losses   : NSLICE f32
#define WS_HCNT   0
#define WS_HSUM   262144
#define WS_TMAX   524288
#define WS_PMAX   524352
#define WS_LOSS   524416
#define WS_USED   524480

__global__ __launch_bounds__(BLOCK) void k_hist(
    const float* __restrict__ net, const float* __restrict__ tgt,
    const float* __restrict__ mp,
    unsigned* __restrict__ hist_cnt, float* __restrict__ hist_sum,
    unsigned* __restrict__ tmax, unsigned* __restrict__ pmax,
    long long nvec /* V/4 per slice */)
{
    __shared__ unsigned lcnt[NBINS];
    __shared__ float    lsum[NBINS];
    const int tid = threadIdx.x;
    for (int i = tid; i < NBINS; i += BLOCK) { lcnt[i] = 0u; lsum[i] = 0.f; }
    __syncthreads();

    const int slice = blockIdx.y;
    const float scale = (float)NBINS / kRange;
    const float4* net4 = (const float4*)net + (size_t)slice * nvec;
    const float4* tgt4 = (const float4*)tgt + (size_t)slice * nvec;
    const float4* mp4  = (const float4*)mp  + (size_t)slice * nvec;

    float ltm = 0.f, lpm = 0.f;
    for (long long i = (long long)blockIdx.x * BLOCK + tid; i < nvec;
         i += (long long)gridDim.x * BLOCK) {
        float4 p = net4[i];
        float4 t = tgt4[i];
        float4 m = mp4[i];
        float pe[4] = {p.x, p.y, p.z, p.w};
        float te[4] = {t.x, t.y, t.z, t.w};
        float me[4] = {m.x, m.y, m.z, m.w};
#pragma unroll
        for (int j = 0; j < 4; ++j) {
            float ce = -te[j] * __logf(pe[j]);      // >= 0
            int bin = (int)(ce * scale);
            bin = bin < 0 ? 0 : (bin > NBINS - 1 ? NBINS - 1 : bin);
            atomicAdd(&lcnt[bin], 1u);              // ds_add_u32
            atomicAdd(&lsum[bin], ce);              // ds_add_f32
            ltm = fmaxf(ltm, te[j]);
            lpm = fmaxf(lpm, me[j]);
        }
    }
    __syncthreads();

    // flush block-private histogram
    for (int i = tid; i < NBINS; i += BLOCK) {
        unsigned c = lcnt[i];
        if (c) {
            atomicAdd(&hist_cnt[slice * NBINS + i], c);
            unsafeAtomicAdd(&hist_sum[slice * NBINS + i], lsum[i]);
        }
    }

    // wave-reduce maxes (non-negative floats -> uint order-preserving)
    for (int off = 32; off; off >>= 1) {
        ltm = fmaxf(ltm, __shfl_down(ltm, off, 64));
        lpm = fmaxf(lpm, __shfl_down(lpm, off, 64));
    }
    if ((tid & 63) == 0) {
        atomicMax(&tmax[slice], __float_as_uint(ltm));
        atomicMax(&pmax[slice], __float_as_uint(lpm));
    }
}

__global__ __launch_bounds__(BLOCK) void k_select(
    const unsigned* __restrict__ hist_cnt, const float* __restrict__ hist_sum,
    const unsigned* __restrict__ tmax, const unsigned* __restrict__ pmax,
    float* __restrict__ losses, unsigned k)
{
    const int slice = blockIdx.x;
    const int tid = threadIdx.x;
    const unsigned* hc = hist_cnt + slice * NBINS;
    const float*    hs = hist_sum + slice * NBINS;

    __shared__ unsigned scnt[BLOCK];
    __shared__ float    ssum[BLOCK];
    __shared__ int      sbin;
    __shared__ unsigned skrem;

    // thread t owns 16 bins in descending order: NBINS-1 - (t*16 + j)
    unsigned mycnt = 0;
#pragma unroll
    for (int j = 0; j < 16; ++j) mycnt += hc[NBINS - 1 - (tid * 16 + j)];
    scnt[tid] = mycnt;
    __syncthreads();

    // exclusive prefix over descending-order thread totals (naive, tiny)
    unsigned P = 0;
    for (int u = 0; u < tid; ++u) P += scnt[u];

    if (P < k && P + mycnt >= k) {       // unique owner of the threshold bin
        unsigned cum = P;
        for (int j = 0; j < 16; ++j) {
            int bin = NBINS - 1 - (tid * 16 + j);
            unsigned c = hc[bin];
            if (cum + c >= k) { sbin = bin; skrem = k - cum; break; }
            cum += c;
        }
    }
    __syncthreads();

    const int bstar = sbin;
    float mysum = 0.f;
#pragma unroll
    for (int j = 0; j < 16; ++j) {
        int bin = NBINS - 1 - (tid * 16 + j);
        if (bin > bstar) mysum += hs[bin];
    }
    ssum[tid] = mysum;
    __syncthreads();
    for (int off = BLOCK / 2; off; off >>= 1) {
        if (tid < off) ssum[tid] += ssum[tid + off];
        __syncthreads();
    }

    if (tid == 0) {
        float total = ssum[0];
        unsigned c = hc[bstar];                    // >= 1 by construction
        float avg = hs[bstar] / (float)c;
        total += (float)skrem * avg;
        float loss = total / (float)k;
        bool active = !((tmax[slice] == 0u) && (pmax[slice] == 0u));
        losses[slice] = active ? loss : 0.0f;
    }
}

__global__ void k_final(const float* __restrict__ losses, float* __restrict__ out)
{
    if (threadIdx.x == 0 && blockIdx.x == 0) {
        float total = 0.f;
        for (int b = 0; b < 4; ++b) {
            float s = 0.f;
            int cnt = 0;
            for (int c = 0; c < 4; ++c) {
                float l = losses[b * 4 + c];
                s += l;
                cnt += (l != 0.0f) ? 1 : 0;
            }
            total += s / (float)cnt;   // cnt==0 -> inf/nan, same as reference
        }
        out[0] = total / 4.0f;
    }
}

extern "C" void kernel_launch(void* const* d_in, const int* in_sizes, int n_in,
                              void* d_out, int out_size, void* d_ws, size_t ws_size,
                              hipStream_t stream) {
    const float* net = (const float*)d_in[0];
    const float* tgt = (const float*)d_in[1];
    const float* mp  = (const float*)d_in[2];
    float* out = (float*)d_out;

    const long long total = in_sizes[0];          // 33,554,432
    const long long V = total / NSLICE;           // 2,097,152
    const long long nvec = V / 4;
    const unsigned k = (unsigned)(V * 10 / 100);  // int(V*10/100) = 209,715

    char* ws = (char*)d_ws;
    unsigned* hist_cnt = (unsigned*)(ws + WS_HCNT);
    float*    hist_sum = (float*)(ws + WS_HSUM);
    unsigned* tmax     = (unsigned*)(ws + WS_TMAX);
    unsigned* pmax     = (unsigned*)(ws + WS_PMAX);
    float*    losses   = (float*)(ws + WS_LOSS);

    hipMemsetAsync(d_ws, 0, WS_USED, stream);

    dim3 grid1(BPS, NSLICE);
    k_hist<<<grid1, BLOCK, 0, stream>>>(net, tgt, mp, hist_cnt, hist_sum,
                                        tmax, pmax, nvec);
    k_select<<<NSLICE, BLOCK, 0, stream>>>(hist_cnt, hist_sum, tmax, pmax,
                                           losses, k);
    k_final<<<1, 64, 0, stream>>>(losses, out);
}